// Round 10
// baseline (463.046 us; speedup 1.0000x reference)
//
#include <hip/hip_runtime.h>
#include <hip/hip_bf16.h>

typedef unsigned char u8;
typedef unsigned int u32;
typedef float f32x16 __attribute__((ext_vector_type(16)));
typedef int i32x4 __attribute__((ext_vector_type(4)));
typedef int i32x8 __attribute__((ext_vector_type(8)));

#define B_SZ 8192
#define D_SZ 768
#define TAU_INV 10.0f
// values scaled by 16 -> logits scaled by 256; exp2 constant = log2(e)*10/256
#define ESCALE 0.05635527503472513f
#define FP8_SCALE 16.0f

// Tiled operand layout: tile = 32 rows x 64 k-bytes = 2048 B, tiles indexed
// (rowgroup rg = row>>5) * 12 + (kblock kb = k>>6).  Within a tile, byte for
// (row r, k) sits at  half*1024 + h*512 + (r&31)*16 + (k&15)
// where half=(k>>4)&1, h=(k>>5)&1.  Consequence: an MFMA fragment read is
// two perfectly-coalesced dwordx4 at  tile_base + lane*16  (+1024).

// HW packed fp32->fp8(e4m3) conversion: v_cvt_pk_fp8_f32, 2 floats per instr
__device__ __forceinline__ u32 pack_fp8x4(float x, float y, float z, float w) {
    int p = __builtin_amdgcn_cvt_pk_fp8_f32(x, y, 0, false);   // low word
    p = __builtin_amdgcn_cvt_pk_fp8_f32(z, w, p, true);        // high word
    return (u32)p;
}

// ---------------- Kernel 1: row norms, fp8 normalize (x16), tiled store, fp32 diag ----------
__global__ __launch_bounds__(256) void norm_kernel(const float4* __restrict__ v,
                                                   const float4* __restrict__ u,
                                                   u32* __restrict__ vn,
                                                   u32* __restrict__ un,
                                                   float* __restrict__ diag) {
    const int wid = threadIdx.x >> 6, lane = threadIdx.x & 63;
    const int row = blockIdx.x * 4 + wid;
    const float4* vr = v + (size_t)row * 192;
    const float4* ur = u + (size_t)row * 192;
    float4 a[3], b[3];
    float sv = 0.f, su = 0.f, sd = 0.f;
#pragma unroll
    for (int c = 0; c < 3; ++c) {
        a[c] = vr[lane + 64 * c];
        b[c] = ur[lane + 64 * c];
        sv += a[c].x * a[c].x + a[c].y * a[c].y + a[c].z * a[c].z + a[c].w * a[c].w;
        su += b[c].x * b[c].x + b[c].y * b[c].y + b[c].z * b[c].z + b[c].w * b[c].w;
        sd += a[c].x * b[c].x + a[c].y * b[c].y + a[c].z * b[c].z + a[c].w * b[c].w;
    }
#pragma unroll
    for (int m = 1; m < 64; m <<= 1) {
        sv += __shfl_xor(sv, m);
        su += __shfl_xor(su, m);
        sd += __shfl_xor(sd, m);
    }
    const float iv = FP8_SCALE / fmaxf(sqrtf(sv), 1e-8f);
    const float iu = FP8_SCALE / fmaxf(sqrtf(su), 1e-8f);
    const int rg = row >> 5, rr = row & 31;
#pragma unroll
    for (int c = 0; c < 3; ++c) {
        u32 pa = pack_fp8x4(a[c].x * iv, a[c].y * iv, a[c].z * iv, a[c].w * iv);
        u32 pb = pack_fp8x4(b[c].x * iu, b[c].y * iu, b[c].z * iu, b[c].w * iu);
        const int e = lane + 64 * c;   // u32-element index within the row (k = 4e)
        const int idx = (rg * 12 + (e >> 4)) * 512 + ((e >> 2) & 1) * 256 +
                        ((e >> 3) & 1) * 128 + rr * 4 + (e & 3);
        vn[idx] = pa;
        un[idx] = pb;
    }
    if (lane == 0) diag[row] = sd * iv * iu * TAU_INV / (FP8_SCALE * FP8_SCALE);
}

// saddr-form fragment load: base is a wave-uniform (SGPR) pointer, off is the
// per-lane VGPR offset (tile*2048 + lane*16).
__device__ __forceinline__ i32x8 ldfrag(const u8* __restrict__ base, u32 off) {
    i32x4 lo = *(const i32x4*)(base + off);
    i32x4 hi = *(const i32x4*)(base + off + 1024);
    return __builtin_shufflevector(lo, hi, 0, 1, 2, 3, 4, 5, 6, 7);
}

__device__ __forceinline__ f32x16 mx_mfma(i32x8 a, i32x8 b, f32x16 c) {
    return __builtin_amdgcn_mfma_scale_f32_32x32x64_f8f6f4(
        a, b, c, 0, 0, 0, 0x7F7F7F7F, 0, 0x7F7F7F7F);
}

// ------- Kernel 2: 256x128 block tile, each wave 128x64 (8 MFMAs/tile-step).
//         NO LDS staging, NO K-loop barriers; saddr loads; 2-slot register pipeline.
//         2 waves/SIMD; high per-wave MFMA density covers L2 latency. -------
__global__ __launch_bounds__(256, 2) void simexp_kernel(const u8* __restrict__ vn,
                                                        const u8* __restrict__ un,
                                                        float* __restrict__ rowP,
                                                        float* __restrict__ colP) {
    __shared__ float rowLds[2][256];
    __shared__ float colLds[2][128];

    const int tid  = threadIdx.x;
    const int wid  = tid >> 6;
    const int lane = tid & 63;
    const int l32  = lane & 31;
    const int h    = lane >> 5;
    const int wr = wid >> 1, wc = wid & 1;   // wave grid: 2 row-halves x 2 col-halves

    // grid: 32 row-blocks (256 rows) x 64 col-blocks (128 cols), 8x8 chunked for L2
    const int id = blockIdx.x;
    const int chunk = id >> 6;               // 32 chunks: 4 rb-chunks x 8 cb-chunks
    const int li = id & 63;
    const int rb = ((chunk >> 3) << 3) + (li >> 3);   // [0,32)
    const int cb = ((chunk & 7) << 3) + (li & 7);     // [0,64)

    // wave-uniform SGPR base pointers (row-group stride = 12 tiles = 24576 B)
    const int aB = __builtin_amdgcn_readfirstlane((rb * 8 + wr * 4) * 24576);
    const int bB = __builtin_amdgcn_readfirstlane((cb * 4 + wc * 2) * 24576);
    const u8* __restrict__ A0 = vn + aB;
    const u8* __restrict__ A1 = A0 + 24576;
    const u8* __restrict__ A2 = A0 + 2 * 24576;
    const u8* __restrict__ A3 = A0 + 3 * 24576;
    const u8* __restrict__ B0 = un + bB;
    const u8* __restrict__ B1 = B0 + 24576;
    u32 voff = (u32)lane * 16;   // per-lane offset; +2048 after each slot-load

    f32x16 acc[4][2];
#pragma unroll
    for (int i = 0; i < 4; ++i)
#pragma unroll
        for (int j = 0; j < 2; ++j)
#pragma unroll
            for (int r = 0; r < 16; ++r) acc[i][j][r] = 0.f;

    i32x8 fa[2][4], fb[2][2];

#define LOAD_SLOT(s)                       \
    {                                      \
        fa[s][0] = ldfrag(A0, voff);       \
        fa[s][1] = ldfrag(A1, voff);       \
        fa[s][2] = ldfrag(A2, voff);       \
        fa[s][3] = ldfrag(A3, voff);       \
        fb[s][0] = ldfrag(B0, voff);       \
        fb[s][1] = ldfrag(B1, voff);       \
        voff += 2048;                      \
    }
#define MFMA_SLOT(s)                                             \
    {                                                            \
        acc[0][0] = mx_mfma(fa[s][0], fb[s][0], acc[0][0]);      \
        acc[1][0] = mx_mfma(fa[s][1], fb[s][0], acc[1][0]);      \
        acc[2][0] = mx_mfma(fa[s][2], fb[s][0], acc[2][0]);      \
        acc[3][0] = mx_mfma(fa[s][3], fb[s][0], acc[3][0]);      \
        acc[0][1] = mx_mfma(fa[s][0], fb[s][1], acc[0][1]);      \
        acc[1][1] = mx_mfma(fa[s][1], fb[s][1], acc[1][1]);      \
        acc[2][1] = mx_mfma(fa[s][2], fb[s][1], acc[2][1]);      \
        acc[3][1] = mx_mfma(fa[s][3], fb[s][1], acc[3][1]);      \
    }

    LOAD_SLOT(0)                     // tile 0
#pragma unroll 1
    for (int it = 0; it < 12; it += 2) {
        LOAD_SLOT(1)                 // tile it+1 — issued before consuming tile it
        MFMA_SLOT(0)
        if (it + 2 < 12) LOAD_SLOT(0)
        MFMA_SLOT(1)
    }

    // Epilogue. 32x32 C/D layout: col = lane&31, row = (reg&3) + 8*(reg>>2) + 4*h
    float rowAcc[64];   // [i*16 + reg]
    float colAcc[2];    // [j]
#pragma unroll
    for (int t = 0; t < 64; ++t) rowAcc[t] = 0.f;
    colAcc[0] = 0.f; colAcc[1] = 0.f;
#pragma unroll
    for (int i = 0; i < 4; ++i)
#pragma unroll
        for (int j = 0; j < 2; ++j)
#pragma unroll
            for (int r = 0; r < 16; ++r) {
                float e = exp2f(acc[i][j][r] * ESCALE);
                rowAcc[i * 16 + r] += e;
                colAcc[j] += e;
            }
    // row sums: reduce across the 32 cols (lanes with same h)
#pragma unroll
    for (int m = 1; m < 32; m <<= 1)
#pragma unroll
        for (int t = 0; t < 64; ++t) rowAcc[t] += __shfl_xor(rowAcc[t], m);
    // col sums: add the other h half (rows)
    colAcc[0] += __shfl_xor(colAcc[0], 32);
    colAcc[1] += __shfl_xor(colAcc[1], 32);

    // writers: row (i,reg) written by lanes with l32==reg (one per h)
#pragma unroll
    for (int i = 0; i < 4; ++i)
#pragma unroll
        for (int t = 0; t < 16; ++t)
            if (l32 == t) {
                int row = wr * 128 + i * 32 + (t & 3) + 8 * (t >> 2) + 4 * h;
                rowLds[wc][row] = rowAcc[i * 16 + t];
            }
    if (h == 0) {
#pragma unroll
        for (int j = 0; j < 2; ++j)
            colLds[wr][wc * 64 + j * 32 + l32] = colAcc[j];
    }
    __syncthreads();
    rowP[(size_t)cb * B_SZ + rb * 256 + tid] = rowLds[0][tid] + rowLds[1][tid];
    if (tid < 128)
        colP[(size_t)rb * B_SZ + cb * 128 + tid] = colLds[0][tid] + colLds[1][tid];
}

// ---------------- Kernel 3: reduce partials, log, subtract diag, mean ----------------
__global__ __launch_bounds__(256) void finalize_kernel(const float* __restrict__ rowP,
                                                       const float* __restrict__ colP,
                                                       const float* __restrict__ diag,
                                                       float* __restrict__ out) {
    const int i = blockIdx.x * 256 + threadIdx.x;
    float rs = 0.f, cs = 0.f;
#pragma unroll 8
    for (int p = 0; p < 64; ++p) rs += rowP[(size_t)p * B_SZ + i];
#pragma unroll 8
    for (int p = 0; p < 32; ++p) cs += colP[(size_t)p * B_SZ + i];
    float contrib = (0.75f * logf(rs) + 0.25f * logf(cs) - diag[i]) * (1.0f / (float)B_SZ);
#pragma unroll
    for (int m = 1; m < 64; m <<= 1) contrib += __shfl_xor(contrib, m);
    __shared__ float red[4];
    const int wid = threadIdx.x >> 6, lane = threadIdx.x & 63;
    if (lane == 0) red[wid] = contrib;
    __syncthreads();
    if (threadIdx.x == 0) atomicAdd(out, red[0] + red[1] + red[2] + red[3]);
}

extern "C" void kernel_launch(void* const* d_in, const int* in_sizes, int n_in,
                              void* d_out, int out_size, void* d_ws, size_t ws_size,
                              hipStream_t stream) {
    const float* v = (const float*)d_in[0];
    const float* u = (const float*)d_in[1];
    char* ws = (char*)d_ws;
    // workspace layout (~15.7 MB)
    u8* vn8    = (u8*)(ws);                     // 8192*768    = 6,291,456 (tiled)
    u8* un8    = (u8*)(ws + 6291456);           // 6,291,456 (tiled)
    float* dg  = (float*)(ws + 12582912);       // 8192*4      = 32,768
    float* rwp = (float*)(ws + 12615680);       // 64*8192*4   = 2,097,152
    float* clp = (float*)(ws + 14712832);       // 32*8192*4   = 1,048,576
    float* out = (float*)d_out;

    hipMemsetAsync(out, 0, sizeof(float), stream);
    hipLaunchKernelGGL(norm_kernel, dim3(2048), dim3(256), 0, stream,
                       (const float4*)v, (const float4*)u, (u32*)vn8, (u32*)un8, dg);
    hipLaunchKernelGGL(simexp_kernel, dim3(2048), dim3(256), 0, stream, vn8, un8, rwp, clp);
    hipLaunchKernelGGL(finalize_kernel, dim3(B_SZ / 256), dim3(256), 0, stream, rwp, clp, dg, out);
}

// Round 11
// 141.105 us; speedup vs baseline: 3.2816x; 3.2816x over previous
//
#include <hip/hip_runtime.h>
#include <hip/hip_bf16.h>

typedef unsigned char u8;
typedef unsigned short u16;
typedef unsigned int u32;
typedef float f32x16 __attribute__((ext_vector_type(16)));
typedef int i32x4 __attribute__((ext_vector_type(4)));
typedef int i32x8 __attribute__((ext_vector_type(8)));

#define B_SZ 8192
#define D_SZ 768
#define TAU_INV 10.0f
// elements scaled by 32 -> logits scaled by 1024; exp2 const = log2(e)*10/1024
#define ESCALE 0.014088818758681283f
#define FP4_SCALE 32.0f

// FP4 tiled operand layout: tile = 32 rows x 64 k-elems x 0.5 B = 1024 B,
// tiles indexed (rowgroup rg = row>>5) * 12 + (kblock kb = k>>6).
// Within a tile, byte for (row r, k) at  h*512 + (r&31)*16 + ((k&31)>>1),
// nibble = k&1 (low nibble = even k), where h=(k>>5)&1.
// Consequence: an MFMA fragment read is ONE coalesced dwordx4 at base+lane*16.

// fp32 -> e2m1 nibble, round-to-nearest (values 0,.5,1,1.5,2,3,4,6; clamp at 6)
__device__ __forceinline__ u32 fp4_enc(float x) {
    float y = fabsf(x);
    u32 n = (u32)(y >= 0.25f) + (u32)(y >= 0.75f) + (u32)(y >= 1.25f) +
            (u32)(y >= 1.75f) + (u32)(y >= 2.5f)  + (u32)(y >= 3.5f) +
            (u32)(y >= 5.0f);
    return n | (x < 0.f ? 8u : 0u);
}

__device__ __forceinline__ u16 fp4_pack4(float x, float y, float z, float w) {
    return (u16)(fp4_enc(x) | (fp4_enc(y) << 4) | (fp4_enc(z) << 8) | (fp4_enc(w) << 12));
}

// ---------------- Kernel 1: row norms, fp4 normalize (x32), tiled store, fp32 diag ----------
__global__ __launch_bounds__(256) void norm_kernel(const float4* __restrict__ v,
                                                   const float4* __restrict__ u,
                                                   u16* __restrict__ vn,
                                                   u16* __restrict__ un,
                                                   float* __restrict__ diag) {
    const int wid = threadIdx.x >> 6, lane = threadIdx.x & 63;
    const int row = blockIdx.x * 4 + wid;
    const float4* vr = v + (size_t)row * 192;
    const float4* ur = u + (size_t)row * 192;
    float4 a[3], b[3];
    float sv = 0.f, su = 0.f, sd = 0.f;
#pragma unroll
    for (int c = 0; c < 3; ++c) {
        a[c] = vr[lane + 64 * c];
        b[c] = ur[lane + 64 * c];
        sv += a[c].x * a[c].x + a[c].y * a[c].y + a[c].z * a[c].z + a[c].w * a[c].w;
        su += b[c].x * b[c].x + b[c].y * b[c].y + b[c].z * b[c].z + b[c].w * b[c].w;
        sd += a[c].x * b[c].x + a[c].y * b[c].y + a[c].z * b[c].z + a[c].w * b[c].w;
    }
#pragma unroll
    for (int m = 1; m < 64; m <<= 1) {
        sv += __shfl_xor(sv, m);
        su += __shfl_xor(su, m);
        sd += __shfl_xor(sd, m);
    }
    const float iv = FP4_SCALE / fmaxf(sqrtf(sv), 1e-8f);
    const float iu = FP4_SCALE / fmaxf(sqrtf(su), 1e-8f);
    const int rg = row >> 5, rr = row & 31;
#pragma unroll
    for (int c = 0; c < 3; ++c) {
        u16 pa = fp4_pack4(a[c].x * iv, a[c].y * iv, a[c].z * iv, a[c].w * iv);
        u16 pb = fp4_pack4(b[c].x * iu, b[c].y * iu, b[c].z * iu, b[c].w * iu);
        const int e = lane + 64 * c;   // float4 index within the row (k = 4e..4e+3)
        // u16 index: tile*(1024/2) + h*256 + rr*8 + (e&7)
        const int idx = (rg * 12 + (e >> 4)) * 512 + ((e >> 3) & 1) * 256 + rr * 8 + (e & 7);
        vn[idx] = pa;
        un[idx] = pb;
    }
    if (lane == 0) diag[row] = sd * iv * iu * TAU_INV / (FP4_SCALE * FP4_SCALE);
}

// saddr-form fp4 fragment load: ONE dwordx4 at wave-uniform base + per-lane off.
// fp4 MFMA reads only v[0:3] of the 8-reg operand; upper half is don't-care.
__device__ __forceinline__ i32x8 ldfrag4(const u8* __restrict__ base, u32 off) {
    i32x4 lo = *(const i32x4*)(base + off);
    return __builtin_shufflevector(lo, lo, 0, 1, 2, 3, 0, 1, 2, 3);
}

__device__ __forceinline__ f32x16 mx_mfma4(i32x8 a, i32x8 b, f32x16 c) {
    // cbsz=4 (A fmt E2M1), blgp=4 (B fmt E2M1), scales = 127 -> 1.0
    return __builtin_amdgcn_mfma_scale_f32_32x32x64_f8f6f4(
        a, b, c, 4, 4, 0, 0x7F7F7F7F, 0, 0x7F7F7F7F);
}

// ------- Kernel 2: 128x128 fp4 MX MFMA tile (BK=64). NO LDS staging, NO K-loop barriers;
//         saddr loads (1 dwordx4/fragment), 2-slot register pipeline, 3 waves/SIMD -------
__global__ __launch_bounds__(256, 3) void simexp_kernel(const u8* __restrict__ vn,
                                                        const u8* __restrict__ un,
                                                        float* __restrict__ rowP,
                                                        float* __restrict__ colP) {
    __shared__ float rowLds[2][128];
    __shared__ float colLds[2][128];

    const int tid  = threadIdx.x;
    const int wid  = tid >> 6;
    const int lane = tid & 63;
    const int l32  = lane & 31;
    const int h    = lane >> 5;
    const int wr = wid >> 1, wc = wid & 1;

    // 8x8 chunked grid for L2 locality
    const int id = blockIdx.x;
    const int chunk = id >> 6;
    const int li = id & 63;
    const int rb = ((chunk >> 3) << 3) + (li >> 3);
    const int cb = ((chunk & 7) << 3) + (li & 7);

    // wave-uniform SGPR base pointers (row-group stride = 12 tiles = 12288 B)
    const int aBase = __builtin_amdgcn_readfirstlane((rb * 4 + wr * 2) * 12288);
    const int bBase = __builtin_amdgcn_readfirstlane((cb * 4 + wc * 2) * 12288);
    const u8* __restrict__ A0 = vn + aBase;
    const u8* __restrict__ A1 = A0 + 12288;
    const u8* __restrict__ B0 = un + bBase;
    const u8* __restrict__ B1 = B0 + 12288;
    u32 voff = (u32)lane * 16;   // per-lane offset; +1024 after each slot-load

    f32x16 acc[2][2];
#pragma unroll
    for (int i = 0; i < 2; ++i)
#pragma unroll
        for (int j = 0; j < 2; ++j)
#pragma unroll
            for (int r = 0; r < 16; ++r) acc[i][j][r] = 0.f;

    i32x8 fa[2][2], fb[2][2];

#define LOAD_SLOT(s)                        \
    {                                       \
        fa[s][0] = ldfrag4(A0, voff);       \
        fa[s][1] = ldfrag4(A1, voff);       \
        fb[s][0] = ldfrag4(B0, voff);       \
        fb[s][1] = ldfrag4(B1, voff);       \
        voff += 1024;                       \
    }
#define MFMA_SLOT(s)                                          \
    {                                                         \
        acc[0][0] = mx_mfma4(fa[s][0], fb[s][0], acc[0][0]);  \
        acc[1][0] = mx_mfma4(fa[s][1], fb[s][0], acc[1][0]);  \
        acc[0][1] = mx_mfma4(fa[s][0], fb[s][1], acc[0][1]);  \
        acc[1][1] = mx_mfma4(fa[s][1], fb[s][1], acc[1][1]);  \
    }

    LOAD_SLOT(0)                     // tile 0
#pragma unroll 1
    for (int it = 0; it < 12; it += 2) {
        LOAD_SLOT(1)                 // tile it+1 — issued before consuming tile it
        MFMA_SLOT(0)
        if (it + 2 < 12) LOAD_SLOT(0)
        MFMA_SLOT(1)
    }

    // Epilogue. 32x32 C/D layout: col = lane&31, row = (reg&3) + 8*(reg>>2) + 4*h
    float rowAcc[32];   // [i*16 + reg]
    float colAcc[2];    // [j]
#pragma unroll
    for (int t = 0; t < 32; ++t) rowAcc[t] = 0.f;
    colAcc[0] = 0.f; colAcc[1] = 0.f;
#pragma unroll
    for (int i = 0; i < 2; ++i)
#pragma unroll
        for (int j = 0; j < 2; ++j)
#pragma unroll
            for (int r = 0; r < 16; ++r) {
                float e = exp2f(acc[i][j][r] * ESCALE);
                rowAcc[i * 16 + r] += e;
                colAcc[j] += e;
            }
    // row sums: reduce across the 32 cols (lanes with same h)
#pragma unroll
    for (int m = 1; m < 32; m <<= 1)
#pragma unroll
        for (int t = 0; t < 32; ++t) rowAcc[t] += __shfl_xor(rowAcc[t], m);
    // col sums: add the other h half (rows)
    colAcc[0] += __shfl_xor(colAcc[0], 32);
    colAcc[1] += __shfl_xor(colAcc[1], 32);

    // writers: row (i,reg) written by lanes with l32==reg (one per h)
#pragma unroll
    for (int i = 0; i < 2; ++i)
#pragma unroll
        for (int t = 0; t < 16; ++t)
            if (l32 == t) {
                int row = wr * 64 + i * 32 + (t & 3) + 8 * (t >> 2) + 4 * h;
                rowLds[wc][row] = rowAcc[i * 16 + t];
            }
    if (h == 0) {
#pragma unroll
        for (int j = 0; j < 2; ++j)
            colLds[wr][wc * 64 + j * 32 + l32] = colAcc[j];
    }
    __syncthreads();
    if (tid < 128) {
        rowP[(size_t)cb * B_SZ + rb * 128 + tid] = rowLds[0][tid] + rowLds[1][tid];
    } else {
        const int t = tid - 128;
        colP[(size_t)rb * B_SZ + cb * 128 + t] = colLds[0][t] + colLds[1][t];
    }
}

// ---------------- Kernel 3: reduce partials, log, subtract diag, mean ----------------
__global__ __launch_bounds__(256) void finalize_kernel(const float* __restrict__ rowP,
                                                       const float* __restrict__ colP,
                                                       const float* __restrict__ diag,
                                                       float* __restrict__ out) {
    const int i = blockIdx.x * 256 + threadIdx.x;
    float rs = 0.f, cs = 0.f;
#pragma unroll 8
    for (int p = 0; p < 64; ++p) {
        rs += rowP[(size_t)p * B_SZ + i];
        cs += colP[(size_t)p * B_SZ + i];
    }
    float contrib = (0.75f * logf(rs) + 0.25f * logf(cs) - diag[i]) * (1.0f / (float)B_SZ);
#pragma unroll
    for (int m = 1; m < 64; m <<= 1) contrib += __shfl_xor(contrib, m);
    __shared__ float red[4];
    const int wid = threadIdx.x >> 6, lane = threadIdx.x & 63;
    if (lane == 0) red[wid] = contrib;
    __syncthreads();
    if (threadIdx.x == 0) atomicAdd(out, red[0] + red[1] + red[2] + red[3]);
}

extern "C" void kernel_launch(void* const* d_in, const int* in_sizes, int n_in,
                              void* d_out, int out_size, void* d_ws, size_t ws_size,
                              hipStream_t stream) {
    const float* v = (const float*)d_in[0];
    const float* u = (const float*)d_in[1];
    char* ws = (char*)d_ws;
    // workspace layout (~10.5 MB)
    u16* vn4   = (u16*)(ws);                    // 8192*384 B  = 3,145,728
    u16* un4   = (u16*)(ws + 3145728);          // 3,145,728
    float* dg  = (float*)(ws + 6291456);        // 8192*4      = 32,768
    float* rwp = (float*)(ws + 6324224);        // 64*8192*4   = 2,097,152
    float* clp = (float*)(ws + 8421376);        // 2,097,152
    float* out = (float*)d_out;

    hipMemsetAsync(out, 0, sizeof(float), stream);
    hipLaunchKernelGGL(norm_kernel, dim3(2048), dim3(256), 0, stream,
                       (const float4*)v, (const float4*)u, vn4, un4, dg);
    hipLaunchKernelGGL(simexp_kernel, dim3(4096), dim3(256), 0, stream,
                       (const u8*)vn4, (const u8*)un4, rwp, clp);
    hipLaunchKernelGGL(finalize_kernel, dim3(B_SZ / 256), dim3(256), 0, stream, rwp, clp, dg, out);
}

// Round 12
// 140.218 us; speedup vs baseline: 3.3023x; 1.0063x over previous
//
#include <hip/hip_runtime.h>
#include <hip/hip_bf16.h>

typedef unsigned char u8;
typedef unsigned short u16;
typedef unsigned int u32;
typedef float f32x16 __attribute__((ext_vector_type(16)));
typedef int i32x4 __attribute__((ext_vector_type(4)));
typedef int i32x8 __attribute__((ext_vector_type(8)));

#define B_SZ 8192
#define D_SZ 768
#define TAU_INV 10.0f
// elements scaled by 32 -> logits scaled by 1024; exp2 const = log2(e)*10/1024
#define ESCALE 0.014088818758681283f
#define FP4_SCALE 32.0f
// Schraudolph fast-exp2: e = as_float((int)(x*K1 + K2)), K1 = ESCALE*2^23,
// K2 = 127*2^23 - sigma, sigma = 0.05645*2^23 (mean-zero error for sums)
#define SCHRAU_K1 118185.58f
#define SCHRAU_K2 1064879685.0f

// FP4 tiled operand layout: tile = 32 rows x 64 k-elems x 0.5 B = 1024 B,
// tiles indexed (rowgroup rg = row>>5) * 12 + (kblock kb = k>>6).
// Within a tile, byte for (row r, k) at  h*512 + (r&31)*16 + ((k&31)>>1),
// nibble = k&1 (low nibble = even k), where h=(k>>5)&1.
// Consequence: an MFMA fragment read is ONE coalesced dwordx4 at base+lane*16.

// fp32 -> e2m1 nibble, round-to-nearest (values 0,.5,1,1.5,2,3,4,6; clamp at 6)
__device__ __forceinline__ u32 fp4_enc(float x) {
    float y = fabsf(x);
    u32 n = (u32)(y >= 0.25f) + (u32)(y >= 0.75f) + (u32)(y >= 1.25f) +
            (u32)(y >= 1.75f) + (u32)(y >= 2.5f)  + (u32)(y >= 3.5f) +
            (u32)(y >= 5.0f);
    return n | (x < 0.f ? 8u : 0u);
}

__device__ __forceinline__ u16 fp4_pack4(float x, float y, float z, float w) {
    return (u16)(fp4_enc(x) | (fp4_enc(y) << 4) | (fp4_enc(z) << 8) | (fp4_enc(w) << 12));
}

// ---------------- Kernel 1: row norms, fp4 normalize (x32), tiled store, fp32 diag ----------
__global__ __launch_bounds__(256) void norm_kernel(const float4* __restrict__ v,
                                                   const float4* __restrict__ u,
                                                   u16* __restrict__ vn,
                                                   u16* __restrict__ un,
                                                   float* __restrict__ diag) {
    const int wid = threadIdx.x >> 6, lane = threadIdx.x & 63;
    const int row = blockIdx.x * 4 + wid;
    const float4* vr = v + (size_t)row * 192;
    const float4* ur = u + (size_t)row * 192;
    float4 a[3], b[3];
    float sv = 0.f, su = 0.f, sd = 0.f;
#pragma unroll
    for (int c = 0; c < 3; ++c) {
        a[c] = vr[lane + 64 * c];
        b[c] = ur[lane + 64 * c];
        sv += a[c].x * a[c].x + a[c].y * a[c].y + a[c].z * a[c].z + a[c].w * a[c].w;
        su += b[c].x * b[c].x + b[c].y * b[c].y + b[c].z * b[c].z + b[c].w * b[c].w;
        sd += a[c].x * b[c].x + a[c].y * b[c].y + a[c].z * b[c].z + a[c].w * b[c].w;
    }
#pragma unroll
    for (int m = 1; m < 64; m <<= 1) {
        sv += __shfl_xor(sv, m);
        su += __shfl_xor(su, m);
        sd += __shfl_xor(sd, m);
    }
    const float iv = FP4_SCALE / fmaxf(sqrtf(sv), 1e-8f);
    const float iu = FP4_SCALE / fmaxf(sqrtf(su), 1e-8f);
    const int rg = row >> 5, rr = row & 31;
#pragma unroll
    for (int c = 0; c < 3; ++c) {
        u16 pa = fp4_pack4(a[c].x * iv, a[c].y * iv, a[c].z * iv, a[c].w * iv);
        u16 pb = fp4_pack4(b[c].x * iu, b[c].y * iu, b[c].z * iu, b[c].w * iu);
        const int e = lane + 64 * c;   // float4 index within the row (k = 4e..4e+3)
        // u16 index: tile*(1024/2) + h*256 + rr*8 + (e&7)
        const int idx = (rg * 12 + (e >> 4)) * 512 + ((e >> 3) & 1) * 256 + rr * 8 + (e & 7);
        vn[idx] = pa;
        un[idx] = pb;
    }
    if (lane == 0) diag[row] = sd * iv * iu * TAU_INV / (FP4_SCALE * FP4_SCALE);
}

// saddr-form fp4 fragment load: ONE dwordx4 at wave-uniform base + per-lane off.
// fp4 MFMA reads only v[0:3] of the 8-reg operand; upper half is don't-care.
__device__ __forceinline__ i32x8 ldfrag4(const u8* __restrict__ base, u32 off) {
    i32x4 lo = *(const i32x4*)(base + off);
    return __builtin_shufflevector(lo, lo, 0, 1, 2, 3, 0, 1, 2, 3);
}

__device__ __forceinline__ f32x16 mx_mfma4(i32x8 a, i32x8 b, f32x16 c) {
    // cbsz=4 (A fmt E2M1), blgp=4 (B fmt E2M1), scales = 127 -> 1.0
    return __builtin_amdgcn_mfma_scale_f32_32x32x64_f8f6f4(
        a, b, c, 4, 4, 0, 0x7F7F7F7F, 0, 0x7F7F7F7F);
}

// ------- Kernel 2: 128x128 fp4 MX MFMA tile (BK=64). NO LDS staging, NO K-loop barriers;
//         saddr loads (1 dwordx4/fragment), 2-slot register pipeline, 4 waves/SIMD;
//         Schraudolph fast-exp2 epilogue (no v_exp_f32) -------
__global__ __launch_bounds__(256, 4) void simexp_kernel(const u8* __restrict__ vn,
                                                        const u8* __restrict__ un,
                                                        float* __restrict__ rowP,
                                                        float* __restrict__ colP) {
    __shared__ float rowLds[2][128];
    __shared__ float colLds[2][128];

    const int tid  = threadIdx.x;
    const int wid  = tid >> 6;
    const int lane = tid & 63;
    const int l32  = lane & 31;
    const int h    = lane >> 5;
    const int wr = wid >> 1, wc = wid & 1;

    // 8x8 chunked grid for L2 locality
    const int id = blockIdx.x;
    const int chunk = id >> 6;
    const int li = id & 63;
    const int rb = ((chunk >> 3) << 3) + (li >> 3);
    const int cb = ((chunk & 7) << 3) + (li & 7);

    // wave-uniform SGPR base pointers (row-group stride = 12 tiles = 12288 B)
    const int aBase = __builtin_amdgcn_readfirstlane((rb * 4 + wr * 2) * 12288);
    const int bBase = __builtin_amdgcn_readfirstlane((cb * 4 + wc * 2) * 12288);
    const u8* __restrict__ A0 = vn + aBase;
    const u8* __restrict__ A1 = A0 + 12288;
    const u8* __restrict__ B0 = un + bBase;
    const u8* __restrict__ B1 = B0 + 12288;
    u32 voff = (u32)lane * 16;   // per-lane offset; +1024 after each slot-load

    f32x16 acc[2][2];
#pragma unroll
    for (int i = 0; i < 2; ++i)
#pragma unroll
        for (int j = 0; j < 2; ++j)
#pragma unroll
            for (int r = 0; r < 16; ++r) acc[i][j][r] = 0.f;

    i32x8 fa[2][2], fb[2][2];

#define LOAD_SLOT(s)                        \
    {                                       \
        fa[s][0] = ldfrag4(A0, voff);       \
        fa[s][1] = ldfrag4(A1, voff);       \
        fb[s][0] = ldfrag4(B0, voff);       \
        fb[s][1] = ldfrag4(B1, voff);       \
        voff += 1024;                       \
    }
#define MFMA_SLOT(s)                                          \
    {                                                         \
        acc[0][0] = mx_mfma4(fa[s][0], fb[s][0], acc[0][0]);  \
        acc[1][0] = mx_mfma4(fa[s][1], fb[s][0], acc[1][0]);  \
        acc[0][1] = mx_mfma4(fa[s][0], fb[s][1], acc[0][1]);  \
        acc[1][1] = mx_mfma4(fa[s][1], fb[s][1], acc[1][1]);  \
    }

    LOAD_SLOT(0)                     // tile 0
#pragma unroll 1
    for (int it = 0; it < 12; it += 2) {
        LOAD_SLOT(1)                 // tile it+1 — issued before consuming tile it
        MFMA_SLOT(0)
        if (it + 2 < 12) LOAD_SLOT(0)
        MFMA_SLOT(1)
    }

    // Epilogue. 32x32 C/D layout: col = lane&31, row = (reg&3) + 8*(reg>>2) + 4*h
    // Schraudolph fast-exp2: one v_fma + one v_cvt per element (vs 1/4-rate v_exp).
    float rowAcc[32];   // [i*16 + reg]
    float colAcc[2];    // [j]
#pragma unroll
    for (int t = 0; t < 32; ++t) rowAcc[t] = 0.f;
    colAcc[0] = 0.f; colAcc[1] = 0.f;
#pragma unroll
    for (int i = 0; i < 2; ++i)
#pragma unroll
        for (int j = 0; j < 2; ++j)
#pragma unroll
            for (int r = 0; r < 16; ++r) {
                float t = fmaf(acc[i][j][r], SCHRAU_K1, SCHRAU_K2);
                float e = __int_as_float((int)t);
                rowAcc[i * 16 + r] += e;
                colAcc[j] += e;
            }
    // row sums: reduce across the 32 cols (lanes with same h)
#pragma unroll
    for (int m = 1; m < 32; m <<= 1)
#pragma unroll
        for (int t = 0; t < 32; ++t) rowAcc[t] += __shfl_xor(rowAcc[t], m);
    // col sums: add the other h half (rows)
    colAcc[0] += __shfl_xor(colAcc[0], 32);
    colAcc[1] += __shfl_xor(colAcc[1], 32);

    // writers: row (i,reg) written by lanes with l32==reg (one per h)
#pragma unroll
    for (int i = 0; i < 2; ++i)
#pragma unroll
        for (int t = 0; t < 16; ++t)
            if (l32 == t) {
                int row = wr * 64 + i * 32 + (t & 3) + 8 * (t >> 2) + 4 * h;
                rowLds[wc][row] = rowAcc[i * 16 + t];
            }
    if (h == 0) {
#pragma unroll
        for (int j = 0; j < 2; ++j)
            colLds[wr][wc * 64 + j * 32 + l32] = colAcc[j];
    }
    __syncthreads();
    if (tid < 128) {
        rowP[(size_t)cb * B_SZ + rb * 128 + tid] = rowLds[0][tid] + rowLds[1][tid];
    } else {
        const int t = tid - 128;
        colP[(size_t)rb * B_SZ + cb * 128 + t] = colLds[0][t] + colLds[1][t];
    }
}

// ---------------- Kernel 3: reduce partials, log, subtract diag, mean ----------------
__global__ __launch_bounds__(256) void finalize_kernel(const float* __restrict__ rowP,
                                                       const float* __restrict__ colP,
                                                       const float* __restrict__ diag,
                                                       float* __restrict__ out) {
    const int i = blockIdx.x * 256 + threadIdx.x;
    float rs = 0.f, cs = 0.f;
#pragma unroll 8
    for (int p = 0; p < 64; ++p) {
        rs += rowP[(size_t)p * B_SZ + i];
        cs += colP[(size_t)p * B_SZ + i];
    }
    float contrib = (0.75f * logf(rs) + 0.25f * logf(cs) - diag[i]) * (1.0f / (float)B_SZ);
#pragma unroll
    for (int m = 1; m < 64; m <<= 1) contrib += __shfl_xor(contrib, m);
    __shared__ float red[4];
    const int wid = threadIdx.x >> 6, lane = threadIdx.x & 63;
    if (lane == 0) red[wid] = contrib;
    __syncthreads();
    if (threadIdx.x == 0) atomicAdd(out, red[0] + red[1] + red[2] + red[3]);
}

extern "C" void kernel_launch(void* const* d_in, const int* in_sizes, int n_in,
                              void* d_out, int out_size, void* d_ws, size_t ws_size,
                              hipStream_t stream) {
    const float* v = (const float*)d_in[0];
    const float* u = (const float*)d_in[1];
    char* ws = (char*)d_ws;
    // workspace layout (~10.5 MB)
    u16* vn4   = (u16*)(ws);                    // 8192*384 B  = 3,145,728
    u16* un4   = (u16*)(ws + 3145728);          // 3,145,728
    float* dg  = (float*)(ws + 6291456);        // 8192*4      = 32,768
    float* rwp = (float*)(ws + 6324224);        // 64*8192*4   = 2,097,152
    float* clp = (float*)(ws + 8421376);        // 2,097,152
    float* out = (float*)d_out;

    hipMemsetAsync(out, 0, sizeof(float), stream);
    hipLaunchKernelGGL(norm_kernel, dim3(2048), dim3(256), 0, stream,
                       (const float4*)v, (const float4*)u, vn4, un4, dg);
    hipLaunchKernelGGL(simexp_kernel, dim3(4096), dim3(256), 0, stream,
                       (const u8*)vn4, (const u8*)un4, rwp, clp);
    hipLaunchKernelGGL(finalize_kernel, dim3(B_SZ / 256), dim3(256), 0, stream, rwp, clp, dg, out);
}